// Round 3
// baseline (2386.101 us; speedup 1.0000x reference)
//
#include <hip/hip_runtime.h>

// GCN: 3 x (GCNConv -> BN(train) -> PReLU), N=100000, E=1600000, 128->64->64->64
// R3: bucketed edge partition (128-node buckets, run-contiguous pair writes)
//     + per-bucket LDS-accumulator aggregation (no per-node CSR, no col scatter)
//     + bf16 hs gather table (halved gather traffic)
//     + BN-apply/PReLU fused into next layer's GEMM X-staging.

constexpr float BN_EPS = 1e-5f;
constexpr int NB_SHIFT = 7;          // 128 nodes per bucket
constexpr int BCAP = 2560;           // pairs capacity per bucket (avg 2048, 11 sigma)
constexpr int PART_CHUNK = 8192;     // edges per partition block

__device__ inline float bf2f(unsigned short h) {
    return __uint_as_float(((unsigned)h) << 16);
}
__device__ inline unsigned short f2bf(float f) {
    unsigned u = __float_as_uint(f);
    unsigned r = (u + 0x7FFFu + ((u >> 16) & 1u)) >> 16;
    return (unsigned short)r;
}

__global__ void count_deg_int(const int* __restrict__ dst, int* __restrict__ degi, int E) {
    int e = blockIdx.x * blockDim.x + threadIdx.x;
    if (e < E) atomicAdd(&degi[dst[e]], 1);
}

__global__ void finalize_dinv(const int* __restrict__ degi, float* __restrict__ dinv, int N) {
    int i = blockIdx.x * blockDim.x + threadIdx.x;
    if (i < N) dinv[i] = rsqrtf((float)degi[i] + 1.0f);  // +1 self-loop
}

// Partition edges into 128-node dst-buckets. Per-block LDS histogram ->
// one global reservation per (block,bucket) -> run-contiguous pair writes.
__global__ __launch_bounds__(256) void partition_edges(
    const int* __restrict__ src, const int* __restrict__ dst,
    int* __restrict__ bcount, uint2* __restrict__ pairs, int E, int nbuck) {
    __shared__ int hist[1024];
    const int t = threadIdx.x;
    for (int i = t; i < nbuck; i += 256) hist[i] = 0;
    __syncthreads();
    const int e0 = blockIdx.x * PART_CHUNK;
    const int e1 = min(e0 + PART_CHUNK, E);
    for (int e = e0 + t; e < e1; e += 256)
        atomicAdd(&hist[dst[e] >> NB_SHIFT], 1);
    __syncthreads();
    for (int i = t; i < nbuck; i += 256) {
        int c = hist[i];
        hist[i] = (c > 0) ? atomicAdd(&bcount[i], c) : 0;  // run base within bucket
    }
    __syncthreads();
    for (int e = e0 + t; e < e1; e += 256) {
        int s = src[e], d = dst[e];
        int b = d >> NB_SHIFT;
        int pos = atomicAdd(&hist[b], 1);
        pairs[(size_t)b * BCAP + pos] = make_uint2((unsigned)s, (unsigned)d);
    }
}

// hs[row][c] = (X'[row][:] @ W[:][c]) * dinv[row], stored bf16.
// FUSE: X' = prelu(X*scale + shift, a) applied per-column during staging
// (X is the raw pre-BN y of the previous layer).
template <int K, bool FUSE>
__global__ __launch_bounds__(256) void gemm_scale(
    const float* __restrict__ X, const float* __restrict__ W,
    const float* __restrict__ dinv, const float* __restrict__ stats_prev,
    const float* __restrict__ a_prev, ushort4* __restrict__ hsb4, int N) {
    static_assert(K % 64 == 0, "K must be multiple of 64");
    __shared__ float Ws[K * 64];
    __shared__ float Xs[64 * 65];

    const int t = threadIdx.x;
    const int rowBase = blockIdx.x * 64;

    for (int q = t; q < K * 16; q += 256)
        ((float4*)Ws)[q] = ((const float4*)W)[q];

    const int tx = t & 15;
    const int ty = t >> 4;

    float acc[4][4];
#pragma unroll
    for (int i = 0; i < 4; ++i)
#pragma unroll
        for (int j = 0; j < 4; ++j) acc[i][j] = 0.f;

#pragma unroll
    for (int kh = 0; kh < K / 64; ++kh) {
        __syncthreads();
#pragma unroll
        for (int j = 0; j < 4; ++j) {
            int q = t + j * 256;
            int r = q >> 4, kk = q & 15;
            int row = rowBase + r;
            float4 v = make_float4(0.f, 0.f, 0.f, 0.f);
            if (row < N) {
                v = *(const float4*)(X + (size_t)row * K + kh * 64 + kk * 4);
                if (FUSE) {
                    int cg = kh * 16 + kk;
                    float4 sc = ((const float4*)(stats_prev + 128))[cg];
                    float4 sh = ((const float4*)(stats_prev + 192))[cg];
                    float4 av = ((const float4*)a_prev)[cg];
                    v.x = fmaf(v.x, sc.x, sh.x); v.x = v.x >= 0.f ? v.x : av.x * v.x;
                    v.y = fmaf(v.y, sc.y, sh.y); v.y = v.y >= 0.f ? v.y : av.y * v.y;
                    v.z = fmaf(v.z, sc.z, sh.z); v.z = v.z >= 0.f ? v.z : av.z * v.z;
                    v.w = fmaf(v.w, sc.w, sh.w); v.w = v.w >= 0.f ? v.w : av.w * v.w;
                }
            }
            float* p = &Xs[r * 65 + kk * 4];
            p[0] = v.x; p[1] = v.y; p[2] = v.z; p[3] = v.w;
        }
        __syncthreads();
#pragma unroll 8
        for (int k = 0; k < 64; ++k) {
            float4 w4 = *(const float4*)&Ws[(kh * 64 + k) * 64 + tx * 4];
#pragma unroll
            for (int i = 0; i < 4; ++i) {
                float xv = Xs[(ty * 4 + i) * 65 + k];
                acc[i][0] = fmaf(xv, w4.x, acc[i][0]);
                acc[i][1] = fmaf(xv, w4.y, acc[i][1]);
                acc[i][2] = fmaf(xv, w4.z, acc[i][2]);
                acc[i][3] = fmaf(xv, w4.w, acc[i][3]);
            }
        }
    }

#pragma unroll
    for (int i = 0; i < 4; ++i) {
        int row = rowBase + ty * 4 + i;
        if (row < N) {
            float dv = dinv[row];
            ushort4 o;
            o.x = f2bf(acc[i][0] * dv);
            o.y = f2bf(acc[i][1] * dv);
            o.z = f2bf(acc[i][2] * dv);
            o.w = f2bf(acc[i][3] * dv);
            hsb4[(size_t)row * 16 + tx] = o;
        }
    }
}

// One block per 128-node bucket: LDS accumulate gathered hs rows, then
// y[n] = dinv[n]*(acc[n] + hs[n]) + b (fp32 out) with fused BN stats.
__global__ __launch_bounds__(256) void aggregate_bn(
    const ushort4* __restrict__ hsb4, const uint2* __restrict__ pairs,
    const int* __restrict__ bcount, const float* __restrict__ dinv,
    const float* __restrict__ bias, float* __restrict__ stats,
    float4* __restrict__ y4, int N) {
    __shared__ float acc[128 * 65];
    __shared__ float lsum[64], lsq[64];
    const int t = threadIdx.x;
    const int b = blockIdx.x;

    for (int i = t; i < 128 * 65; i += 256) acc[i] = 0.f;
    if (t < 64) { lsum[t] = 0.f; lsq[t] = 0.f; }
    __syncthreads();

    const int cnt = bcount[b];
    const uint2* pp = pairs + (size_t)b * BCAP;
    const int g = t >> 4;     // edge group 0..15
    const int fl = t & 15;    // float4 feature index

    uint2 pr = (g < cnt) ? pp[g] : make_uint2(0u, 0u);
    for (int e = g; e < cnt; e += 16) {
        uint2 cur = pr;
        if (e + 16 < cnt) pr = pp[e + 16];
        ushort4 rv = hsb4[(size_t)cur.x * 16 + fl];
        int local = (int)(cur.y & 127u);
        float* ap = &acc[local * 65 + fl * 4];
        atomicAdd(ap + 0, bf2f(rv.x));
        atomicAdd(ap + 1, bf2f(rv.y));
        atomicAdd(ap + 2, bf2f(rv.z));
        atomicAdd(ap + 3, bf2f(rv.w));
    }
    __syncthreads();

    // write-out: thread t covers rows (t>>4)+16j, f4-col t&15
    float4 s = make_float4(0.f, 0.f, 0.f, 0.f);
    float4 q = make_float4(0.f, 0.f, 0.f, 0.f);
    const float4 b4 = ((const float4*)bias)[fl];
    const int nodeBase = b << NB_SHIFT;
#pragma unroll
    for (int j = 0; j < 8; ++j) {
        int local = (t >> 4) + j * 16;
        int n = nodeBase + local;
        if (n >= N) break;
        ushort4 rv = hsb4[(size_t)n * 16 + fl];  // self term
        float dv = dinv[n];
        float* ap = &acc[local * 65 + fl * 4];
        float4 yv;
        yv.x = fmaf(dv, ap[0] + bf2f(rv.x), b4.x);
        yv.y = fmaf(dv, ap[1] + bf2f(rv.y), b4.y);
        yv.z = fmaf(dv, ap[2] + bf2f(rv.z), b4.z);
        yv.w = fmaf(dv, ap[3] + bf2f(rv.w), b4.w);
        y4[(size_t)n * 16 + fl] = yv;
        s.x += yv.x; s.y += yv.y; s.z += yv.z; s.w += yv.w;
        q.x = fmaf(yv.x, yv.x, q.x); q.y = fmaf(yv.y, yv.y, q.y);
        q.z = fmaf(yv.z, yv.z, q.z); q.w = fmaf(yv.w, yv.w, q.w);
    }
    atomicAdd(&lsum[fl * 4 + 0], s.x); atomicAdd(&lsum[fl * 4 + 1], s.y);
    atomicAdd(&lsum[fl * 4 + 2], s.z); atomicAdd(&lsum[fl * 4 + 3], s.w);
    atomicAdd(&lsq[fl * 4 + 0], q.x); atomicAdd(&lsq[fl * 4 + 1], q.y);
    atomicAdd(&lsq[fl * 4 + 2], q.z); atomicAdd(&lsq[fl * 4 + 3], q.w);
    __syncthreads();
    if (t < 64) atomicAdd(&stats[t], lsum[t]);
    else if (t < 128) atomicAdd(&stats[64 + (t - 64)], lsq[t - 64]);
}

__global__ void bn_final(float* __restrict__ stats, const float* __restrict__ g,
                         const float* __restrict__ be, float invN) {
    int c = threadIdx.x;  // 64 threads
    float mu = stats[c] * invN;
    float var = stats[64 + c] * invN - mu * mu;
    float sc = g[c] * rsqrtf(var + BN_EPS);
    stats[128 + c] = sc;
    stats[192 + c] = be[c] - mu * sc;
}

// final layer: out = prelu(y*scale + shift, a)
__global__ __launch_bounds__(256) void bn_apply(
    const float4* __restrict__ y4, const float* __restrict__ stats,
    const float* __restrict__ a, float4* __restrict__ out4, int total4) {
    int i = blockIdx.x * blockDim.x + threadIdx.x;
    if (i >= total4) return;
    int cg = (i & 15) * 4;
    float4 v = y4[i];
    float4 o;
    { float z = fmaf(v.x, stats[128 + cg + 0], stats[192 + cg + 0]); o.x = z >= 0.f ? z : a[cg + 0] * z; }
    { float z = fmaf(v.y, stats[128 + cg + 1], stats[192 + cg + 1]); o.y = z >= 0.f ? z : a[cg + 1] * z; }
    { float z = fmaf(v.z, stats[128 + cg + 2], stats[192 + cg + 2]); o.z = z >= 0.f ? z : a[cg + 2] * z; }
    { float z = fmaf(v.w, stats[128 + cg + 3], stats[192 + cg + 3]); o.w = z >= 0.f ? z : a[cg + 3] * z; }
    out4[i] = o;
}

extern "C" void kernel_launch(void* const* d_in, const int* in_sizes, int n_in,
                              void* d_out, int out_size, void* d_ws, size_t ws_size,
                              hipStream_t stream) {
    const float* x  = (const float*)d_in[0];
    const int*   ei = (const int*)d_in[1];
    const int N = in_sizes[0] / 128;
    const int E = in_sizes[1] / 2;
    const int* srcp = ei;
    const int* dstp = ei + E;

    const float* W1 = (const float*)d_in[2];
    const float* b1 = (const float*)d_in[3];
    const float* g1 = (const float*)d_in[4];
    const float* be1 = (const float*)d_in[5];
    const float* a1 = (const float*)d_in[6];
    const float* W2 = (const float*)d_in[7];
    const float* b2 = (const float*)d_in[8];
    const float* g2 = (const float*)d_in[9];
    const float* be2 = (const float*)d_in[10];
    const float* a2 = (const float*)d_in[11];
    const float* W3 = (const float*)d_in[12];
    const float* b3 = (const float*)d_in[13];
    const float* g3 = (const float*)d_in[14];
    const float* be3 = (const float*)d_in[15];
    const float* a3 = (const float*)d_in[16];

    const int nbuck = (N + 127) >> NB_SHIFT;  // 782

    // ws layout (4B units):
    // dinv[N] | degi[N] | bcount[1024] | stats[768] | pairs[nbuck*BCAP*2] |
    // hsb[N*32 (bf16 N*64)] | ybuf[N*64]
    float* ws = (float*)d_ws;
    float* dinv   = ws;
    int*   degi   = (int*)(ws + N);
    int*   bcount = (int*)(ws + 2 * (size_t)N);
    float* stats  = ws + 2 * (size_t)N + 1024;         // stats1|stats2|stats3
    uint2* pairs  = (uint2*)(ws + 2 * (size_t)N + 1024 + 768);
    float* hsbf   = ws + 2 * (size_t)N + 1024 + 768 + 2 * (size_t)nbuck * BCAP;
    ushort4* hsb4 = (ushort4*)hsbf;
    float* ybuf   = hsbf + (size_t)N * 32;

    float* stats1 = stats, *stats2 = stats + 256, *stats3 = stats + 512;

    // one memset covers degi + bcount + stats
    hipMemsetAsync(degi, 0, ((size_t)N + 1024 + 768) * sizeof(float), stream);
    count_deg_int<<<(E + 255) / 256, 256, 0, stream>>>(dstp, degi, E);
    finalize_dinv<<<(N + 255) / 256, 256, 0, stream>>>(degi, dinv, N);
    partition_edges<<<(E + PART_CHUNK - 1) / PART_CHUNK, 256, 0, stream>>>(
        srcp, dstp, bcount, pairs, E, nbuck);

    const int gemmGrid = (N + 63) / 64;
    const int applyGrid = (N * 16 + 255) / 256;
    const float invN = 1.0f / (float)N;

    // ---- layer 1 ----
    gemm_scale<128, false><<<gemmGrid, 256, 0, stream>>>(x, W1, dinv, nullptr, nullptr, hsb4, N);
    aggregate_bn<<<nbuck, 256, 0, stream>>>(hsb4, pairs, bcount, dinv, b1, stats1,
                                            (float4*)ybuf, N);
    bn_final<<<1, 64, 0, stream>>>(stats1, g1, be1, invN);

    // ---- layer 2 (apply BN1+PReLU1 fused into X staging) ----
    gemm_scale<64, true><<<gemmGrid, 256, 0, stream>>>(ybuf, W2, dinv, stats1, a1, hsb4, N);
    aggregate_bn<<<nbuck, 256, 0, stream>>>(hsb4, pairs, bcount, dinv, b2, stats2,
                                            (float4*)ybuf, N);
    bn_final<<<1, 64, 0, stream>>>(stats2, g2, be2, invN);

    // ---- layer 3 ----
    gemm_scale<64, true><<<gemmGrid, 256, 0, stream>>>(ybuf, W3, dinv, stats2, a2, hsb4, N);
    aggregate_bn<<<nbuck, 256, 0, stream>>>(hsb4, pairs, bcount, dinv, b3, stats3,
                                            (float4*)ybuf, N);
    bn_final<<<1, 64, 0, stream>>>(stats3, g3, be3, invN);

    bn_apply<<<applyGrid, 256, 0, stream>>>((const float4*)ybuf, stats3, a3,
                                            (float4*)d_out, N * 16);
}

// Round 4
// 633.977 us; speedup vs baseline: 3.7637x; 3.7637x over previous
//
#include <hip/hip_runtime.h>

// GCN: 3 x (GCNConv -> BN(train) -> PReLU), N=100000, E=1600000, 128->64->64->64
// R4: R2's high-TLP register-accumulation gather aggregation (2048 blocks,
//     1 wave/node) over a bf16 hs table + low-amplification CSR build
//     (bucket partition -> per-bucket LDS-cursor fill, contiguous col writes)
//     + BN-apply/PReLU fused into next layer's GEMM X-staging.
// R3 lesson: per-bucket LDS-atomic aggregation = latency-bound disaster
// (782 blocks, 1.5% VALUBusy, 699us/layer). Register accum + big grids win.

constexpr float BN_EPS = 1e-5f;
constexpr int NB_SHIFT = 7;          // 128 nodes per bucket
constexpr int BCAP = 2560;           // pairs per bucket (avg 2048, ~11 sigma)
constexpr int PART_CHUNK = 8192;     // edges per partition block

__device__ inline float bf2f(unsigned short h) {
    return __uint_as_float(((unsigned)h) << 16);
}
__device__ inline unsigned short f2bf(float f) {
    unsigned u = __float_as_uint(f);
    unsigned r = (u + 0x7FFFu + ((u >> 16) & 1u)) >> 16;
    return (unsigned short)r;
}

__global__ void count_deg_int(const int* __restrict__ dst, int* __restrict__ degi, int E) {
    int e = blockIdx.x * blockDim.x + threadIdx.x;
    if (e < E) atomicAdd(&degi[dst[e]], 1);
}

__global__ void finalize_dinv(const int* __restrict__ degi, float* __restrict__ dinv, int N) {
    int i = blockIdx.x * blockDim.x + threadIdx.x;
    if (i < N) dinv[i] = rsqrtf((float)degi[i] + 1.0f);  // +1 self-loop
}

// inclusive scan of degi within 256-blocks -> rowend; block totals -> blocksum
__global__ __launch_bounds__(256) void scan1(const int* __restrict__ degi,
                                             int* __restrict__ rowend,
                                             int* __restrict__ blocksum, int N) {
    __shared__ int tmp[256];
    int t = threadIdx.x;
    int i = blockIdx.x * 256 + t;
    int v = (i < N) ? degi[i] : 0;
    tmp[t] = v;
    __syncthreads();
    for (int off = 1; off < 256; off <<= 1) {
        int u = (t >= off) ? tmp[t - off] : 0;
        __syncthreads();
        tmp[t] += u;
        __syncthreads();
    }
    if (i < N) rowend[i] = tmp[t];
    if (t == 255) blocksum[blockIdx.x] = tmp[255];
}

__global__ __launch_bounds__(512) void scan2(int* __restrict__ blocksum, int nb) {
    __shared__ int tmp[512];
    int t = threadIdx.x;
    int v = (t < nb) ? blocksum[t] : 0;
    tmp[t] = v;
    __syncthreads();
    for (int off = 1; off < 512; off <<= 1) {
        int u = (t >= off) ? tmp[t - off] : 0;
        __syncthreads();
        tmp[t] += u;
        __syncthreads();
    }
    if (t < nb) blocksum[t] = tmp[t] - v;  // exclusive
}

__global__ __launch_bounds__(256) void scan3(int* __restrict__ rowend,
                                             const int* __restrict__ blocksum, int N) {
    int i = blockIdx.x * 256 + threadIdx.x;
    if (i < N) rowend[i] += blocksum[blockIdx.x];
}

// Partition edges into 128-node dst-buckets (run-contiguous pair writes).
__global__ __launch_bounds__(256) void partition_edges(
    const int* __restrict__ src, const int* __restrict__ dst,
    int* __restrict__ bcount, uint2* __restrict__ pairs, int E, int nbuck) {
    __shared__ int hist[1024];
    const int t = threadIdx.x;
    for (int i = t; i < nbuck; i += 256) hist[i] = 0;
    __syncthreads();
    const int e0 = blockIdx.x * PART_CHUNK;
    const int e1 = min(e0 + PART_CHUNK, E);
    for (int e = e0 + t; e < e1; e += 256)
        atomicAdd(&hist[dst[e] >> NB_SHIFT], 1);
    __syncthreads();
    for (int i = t; i < nbuck; i += 256) {
        int c = hist[i];
        hist[i] = (c > 0) ? atomicAdd(&bcount[i], c) : 0;  // run base within bucket
    }
    __syncthreads();
    for (int e = e0 + t; e < e1; e += 256) {
        int s = src[e], d = dst[e];
        int b = d >> NB_SHIFT;
        int pos = atomicAdd(&hist[b], 1);
        pairs[(size_t)b * BCAP + pos] = make_uint2((unsigned)s, (unsigned)d);
    }
}

// One block per bucket: LDS cursors, write col within an ~8KB window.
__global__ __launch_bounds__(256) void fill_csr_bucket(
    const uint2* __restrict__ pairs, const int* __restrict__ bcount,
    const int* __restrict__ rowend, const int* __restrict__ degi,
    int* __restrict__ col, int N) {
    __shared__ int lcur[128];
    const int b = blockIdx.x, t = threadIdx.x;
    const int nodeBase = b << NB_SHIFT;
    if (t < 128) {
        int n = nodeBase + t;
        lcur[t] = (n < N) ? rowend[n] - degi[n] : 0;
    }
    __syncthreads();
    const int cnt = bcount[b];
    const uint2* pp = pairs + (size_t)b * BCAP;
    for (int e = t; e < cnt; e += 256) {
        uint2 pr = pp[e];
        int pos = atomicAdd(&lcur[pr.y & 127u], 1);
        col[pos] = (int)pr.x;
    }
}

// hs[row][c] = (X'[row][:] @ W[:][c]) * dinv[row], stored bf16.
// FUSE: X' = prelu(X*scale + shift, a) applied per-column during staging.
template <int K, bool FUSE>
__global__ __launch_bounds__(256) void gemm_scale(
    const float* __restrict__ X, const float* __restrict__ W,
    const float* __restrict__ dinv, const float* __restrict__ stats_prev,
    const float* __restrict__ a_prev, ushort4* __restrict__ hsb4, int N) {
    static_assert(K % 64 == 0, "K must be multiple of 64");
    __shared__ float Ws[K * 64];
    __shared__ float Xs[64 * 65];

    const int t = threadIdx.x;
    const int rowBase = blockIdx.x * 64;

    for (int q = t; q < K * 16; q += 256)
        ((float4*)Ws)[q] = ((const float4*)W)[q];

    const int tx = t & 15;
    const int ty = t >> 4;

    float acc[4][4];
#pragma unroll
    for (int i = 0; i < 4; ++i)
#pragma unroll
        for (int j = 0; j < 4; ++j) acc[i][j] = 0.f;

#pragma unroll
    for (int kh = 0; kh < K / 64; ++kh) {
        __syncthreads();
#pragma unroll
        for (int j = 0; j < 4; ++j) {
            int q = t + j * 256;
            int r = q >> 4, kk = q & 15;
            int row = rowBase + r;
            float4 v = make_float4(0.f, 0.f, 0.f, 0.f);
            if (row < N) {
                v = *(const float4*)(X + (size_t)row * K + kh * 64 + kk * 4);
                if (FUSE) {
                    int cg = kh * 16 + kk;
                    float4 sc = ((const float4*)(stats_prev + 128))[cg];
                    float4 sh = ((const float4*)(stats_prev + 192))[cg];
                    float4 av = ((const float4*)a_prev)[cg];
                    v.x = fmaf(v.x, sc.x, sh.x); v.x = v.x >= 0.f ? v.x : av.x * v.x;
                    v.y = fmaf(v.y, sc.y, sh.y); v.y = v.y >= 0.f ? v.y : av.y * v.y;
                    v.z = fmaf(v.z, sc.z, sh.z); v.z = v.z >= 0.f ? v.z : av.z * v.z;
                    v.w = fmaf(v.w, sc.w, sh.w); v.w = v.w >= 0.f ? v.w : av.w * v.w;
                }
            }
            float* p = &Xs[r * 65 + kk * 4];
            p[0] = v.x; p[1] = v.y; p[2] = v.z; p[3] = v.w;
        }
        __syncthreads();
#pragma unroll 8
        for (int k = 0; k < 64; ++k) {
            float4 w4 = *(const float4*)&Ws[(kh * 64 + k) * 64 + tx * 4];
#pragma unroll
            for (int i = 0; i < 4; ++i) {
                float xv = Xs[(ty * 4 + i) * 65 + k];
                acc[i][0] = fmaf(xv, w4.x, acc[i][0]);
                acc[i][1] = fmaf(xv, w4.y, acc[i][1]);
                acc[i][2] = fmaf(xv, w4.z, acc[i][2]);
                acc[i][3] = fmaf(xv, w4.w, acc[i][3]);
            }
        }
    }

#pragma unroll
    for (int i = 0; i < 4; ++i) {
        int row = rowBase + ty * 4 + i;
        if (row < N) {
            float dv = dinv[row];
            ushort4 o;
            o.x = f2bf(acc[i][0] * dv);
            o.y = f2bf(acc[i][1] * dv);
            o.z = f2bf(acc[i][2] * dv);
            o.w = f2bf(acc[i][3] * dv);
            hsb4[(size_t)row * 16 + tx] = o;
        }
    }
}

// One wave per node: y[n] = dinv[n]*(hs[n] + sum_{src->n} hs[src]) + b
// Register accumulation; fused per-feature BN stats.
__global__ __launch_bounds__(256) void aggregate_bn(
    const ushort4* __restrict__ hsb4, const int* __restrict__ col,
    const int* __restrict__ rowend, const int* __restrict__ degi,
    const float* __restrict__ dinv, const float* __restrict__ bias,
    float* __restrict__ stats, float4* __restrict__ y4, int N) {
    const int t = threadIdx.x;
    const int lane = t & 63;
    const int wid = t >> 6;      // wave in block (0..3)
    const int fl = lane & 15;    // float4 feature index
    const int eg = lane >> 4;    // edge subgroup (0..3)

    __shared__ float lsum[64], lsq[64];
    if (t < 64) { lsum[t] = 0.f; lsq[t] = 0.f; }
    __syncthreads();

    float4 ssum = make_float4(0.f, 0.f, 0.f, 0.f);
    float4 ssq  = make_float4(0.f, 0.f, 0.f, 0.f);
    const float4 b4 = ((const float4*)bias)[fl];
    const int waveStride = gridDim.x * 4;

    for (int n = blockIdx.x * 4 + wid; n < N; n += waveStride) {
        int deg = degi[n];
        int start = rowend[n] - deg;
        float4 acc = make_float4(0.f, 0.f, 0.f, 0.f);
        for (int i = eg; i < deg; i += 4) {
            int s = col[start + i];
            ushort4 rv = hsb4[(size_t)s * 16 + fl];
            acc.x += bf2f(rv.x); acc.y += bf2f(rv.y);
            acc.z += bf2f(rv.z); acc.w += bf2f(rv.w);
        }
        acc.x += __shfl_xor(acc.x, 16); acc.y += __shfl_xor(acc.y, 16);
        acc.z += __shfl_xor(acc.z, 16); acc.w += __shfl_xor(acc.w, 16);
        acc.x += __shfl_xor(acc.x, 32); acc.y += __shfl_xor(acc.y, 32);
        acc.z += __shfl_xor(acc.z, 32); acc.w += __shfl_xor(acc.w, 32);
        if (eg == 0) {
            ushort4 sv = hsb4[(size_t)n * 16 + fl];
            float dv = dinv[n];
            float4 yv;
            yv.x = fmaf(dv, acc.x + bf2f(sv.x), b4.x);
            yv.y = fmaf(dv, acc.y + bf2f(sv.y), b4.y);
            yv.z = fmaf(dv, acc.z + bf2f(sv.z), b4.z);
            yv.w = fmaf(dv, acc.w + bf2f(sv.w), b4.w);
            y4[(size_t)n * 16 + fl] = yv;
            ssum.x += yv.x; ssum.y += yv.y; ssum.z += yv.z; ssum.w += yv.w;
            ssq.x = fmaf(yv.x, yv.x, ssq.x); ssq.y = fmaf(yv.y, yv.y, ssq.y);
            ssq.z = fmaf(yv.z, yv.z, ssq.z); ssq.w = fmaf(yv.w, yv.w, ssq.w);
        }
    }
    if (eg == 0) {
        atomicAdd(&lsum[fl * 4 + 0], ssum.x); atomicAdd(&lsum[fl * 4 + 1], ssum.y);
        atomicAdd(&lsum[fl * 4 + 2], ssum.z); atomicAdd(&lsum[fl * 4 + 3], ssum.w);
        atomicAdd(&lsq[fl * 4 + 0], ssq.x);  atomicAdd(&lsq[fl * 4 + 1], ssq.y);
        atomicAdd(&lsq[fl * 4 + 2], ssq.z);  atomicAdd(&lsq[fl * 4 + 3], ssq.w);
    }
    __syncthreads();
    if (t < 64) atomicAdd(&stats[t], lsum[t]);
    else if (t < 128) atomicAdd(&stats[64 + (t - 64)], lsq[t - 64]);
}

__global__ void bn_final(float* __restrict__ stats, const float* __restrict__ g,
                         const float* __restrict__ be, float invN) {
    int c = threadIdx.x;  // 64 threads
    float mu = stats[c] * invN;
    float var = stats[64 + c] * invN - mu * mu;
    float sc = g[c] * rsqrtf(var + BN_EPS);
    stats[128 + c] = sc;
    stats[192 + c] = be[c] - mu * sc;
}

// final layer only: out = prelu(y*scale + shift, a)
__global__ __launch_bounds__(256) void bn_apply(
    const float4* __restrict__ y4, const float* __restrict__ stats,
    const float* __restrict__ a, float4* __restrict__ out4, int total4) {
    int i = blockIdx.x * blockDim.x + threadIdx.x;
    if (i >= total4) return;
    int cg = (i & 15) * 4;
    float4 v = y4[i];
    float4 o;
    { float z = fmaf(v.x, stats[128 + cg + 0], stats[192 + cg + 0]); o.x = z >= 0.f ? z : a[cg + 0] * z; }
    { float z = fmaf(v.y, stats[128 + cg + 1], stats[192 + cg + 1]); o.y = z >= 0.f ? z : a[cg + 1] * z; }
    { float z = fmaf(v.z, stats[128 + cg + 2], stats[192 + cg + 2]); o.z = z >= 0.f ? z : a[cg + 2] * z; }
    { float z = fmaf(v.w, stats[128 + cg + 3], stats[192 + cg + 3]); o.w = z >= 0.f ? z : a[cg + 3] * z; }
    out4[i] = o;
}

extern "C" void kernel_launch(void* const* d_in, const int* in_sizes, int n_in,
                              void* d_out, int out_size, void* d_ws, size_t ws_size,
                              hipStream_t stream) {
    const float* x  = (const float*)d_in[0];
    const int*   ei = (const int*)d_in[1];
    const int N = in_sizes[0] / 128;
    const int E = in_sizes[1] / 2;
    const int* srcp = ei;
    const int* dstp = ei + E;

    const float* W1 = (const float*)d_in[2];
    const float* b1 = (const float*)d_in[3];
    const float* g1 = (const float*)d_in[4];
    const float* be1 = (const float*)d_in[5];
    const float* a1 = (const float*)d_in[6];
    const float* W2 = (const float*)d_in[7];
    const float* b2 = (const float*)d_in[8];
    const float* g2 = (const float*)d_in[9];
    const float* be2 = (const float*)d_in[10];
    const float* a2 = (const float*)d_in[11];
    const float* W3 = (const float*)d_in[12];
    const float* b3 = (const float*)d_in[13];
    const float* g3 = (const float*)d_in[14];
    const float* be3 = (const float*)d_in[15];
    const float* a3 = (const float*)d_in[16];

    const int nbuck = (N + 127) >> NB_SHIFT;  // 782

    // ws layout (4B units):
    // dinv[N] | degi[N] | bcount[1024] | stats[768] | blocksum[512] |
    // rowend[N] | col[E] | pairs[nbuck*BCAP*2] | hsb[N*32] | ybuf[N*64]
    float* ws = (float*)d_ws;
    float* dinv     = ws;
    int*   degi     = (int*)(ws + N);
    int*   bcount   = (int*)(ws + 2 * (size_t)N);
    float* stats    = ws + 2 * (size_t)N + 1024;
    int*   blocksum = (int*)(ws + 2 * (size_t)N + 1792);
    int*   rowend   = (int*)(ws + 2 * (size_t)N + 2304);
    int*   col      = (int*)(ws + 3 * (size_t)N + 2304);
    uint2* pairs    = (uint2*)(ws + 3 * (size_t)N + 2304 + E);
    float* hsbf     = ws + 3 * (size_t)N + 2304 + E + 2 * (size_t)nbuck * BCAP;
    ushort4* hsb4   = (ushort4*)hsbf;
    float* ybuf     = hsbf + (size_t)N * 32;

    float* stats1 = stats, *stats2 = stats + 256, *stats3 = stats + 512;

    const int nb1 = (N + 255) / 256;  // scan blocks (must be <= 512)

    // one memset covers degi + bcount + stats
    hipMemsetAsync(degi, 0, ((size_t)N + 1024 + 768) * sizeof(int), stream);
    count_deg_int<<<(E + 255) / 256, 256, 0, stream>>>(dstp, degi, E);
    finalize_dinv<<<nb1, 256, 0, stream>>>(degi, dinv, N);
    scan1<<<nb1, 256, 0, stream>>>(degi, rowend, blocksum, N);
    scan2<<<1, 512, 0, stream>>>(blocksum, nb1);
    scan3<<<nb1, 256, 0, stream>>>(rowend, blocksum, N);
    partition_edges<<<(E + PART_CHUNK - 1) / PART_CHUNK, 256, 0, stream>>>(
        srcp, dstp, bcount, pairs, E, nbuck);
    fill_csr_bucket<<<nbuck, 256, 0, stream>>>(pairs, bcount, rowend, degi, col, N);

    const int gemmGrid = (N + 63) / 64;
    const int aggGrid = 2048;
    const int applyGrid = (N * 16 + 255) / 256;
    const float invN = 1.0f / (float)N;

    // ---- layer 1 ----
    gemm_scale<128, false><<<gemmGrid, 256, 0, stream>>>(x, W1, dinv, nullptr, nullptr, hsb4, N);
    aggregate_bn<<<aggGrid, 256, 0, stream>>>(hsb4, col, rowend, degi, dinv, b1,
                                              stats1, (float4*)ybuf, N);
    bn_final<<<1, 64, 0, stream>>>(stats1, g1, be1, invN);

    // ---- layer 2 (BN1+PReLU1 fused into X staging) ----
    gemm_scale<64, true><<<gemmGrid, 256, 0, stream>>>(ybuf, W2, dinv, stats1, a1, hsb4, N);
    aggregate_bn<<<aggGrid, 256, 0, stream>>>(hsb4, col, rowend, degi, dinv, b2,
                                              stats2, (float4*)ybuf, N);
    bn_final<<<1, 64, 0, stream>>>(stats2, g2, be2, invN);

    // ---- layer 3 ----
    gemm_scale<64, true><<<gemmGrid, 256, 0, stream>>>(ybuf, W3, dinv, stats2, a2, hsb4, N);
    aggregate_bn<<<aggGrid, 256, 0, stream>>>(hsb4, col, rowend, degi, dinv, b3,
                                              stats3, (float4*)ybuf, N);
    bn_final<<<1, 64, 0, stream>>>(stats3, g3, be3, invN);

    bn_apply<<<applyGrid, 256, 0, stream>>>((const float4*)ybuf, stats3, a3,
                                            (float4*)d_out, N * 16);
}

// Round 5
// 608.564 us; speedup vs baseline: 3.9209x; 1.0418x over previous
//
#include <hip/hip_runtime.h>

// GCN: 3 x (GCNConv -> BN(train) -> PReLU), N=100000, E=1600000, 128->64->64->64
// R5: aggregate gather gets 4-deep MLP unroll (R4 was latency-bound: VALUBusy
//     15%, hbm 15%, one outstanding gather per lane-group). CSR build loses
//     count_deg + N-wide scans: per-bucket LDS histogram/scan in fill kernel
//     produces rowstart + dinv directly; 1-block scan over 782 bucket counts.
// R3 lesson: per-bucket LDS-atomic aggregation = latency disaster; register
// accumulation + big grids win.

constexpr float BN_EPS = 1e-5f;
constexpr int NB_SHIFT = 7;          // 128 nodes per bucket
constexpr int BCAP = 2560;           // pairs per bucket (avg 2048, ~11 sigma)
constexpr int PART_CHUNK = 8192;     // edges per partition block

__device__ inline float bf2f(unsigned short h) {
    return __uint_as_float(((unsigned)h) << 16);
}
__device__ inline unsigned short f2bf(float f) {
    unsigned u = __float_as_uint(f);
    unsigned r = (u + 0x7FFFu + ((u >> 16) & 1u)) >> 16;
    return (unsigned short)r;
}

// Partition edges into 128-node dst-buckets (run-contiguous pair writes).
__global__ __launch_bounds__(256) void partition_edges(
    const int* __restrict__ src, const int* __restrict__ dst,
    int* __restrict__ bcount, uint2* __restrict__ pairs, int E, int nbuck) {
    __shared__ int hist[1024];
    const int t = threadIdx.x;
    for (int i = t; i < nbuck; i += 256) hist[i] = 0;
    __syncthreads();
    const int e0 = blockIdx.x * PART_CHUNK;
    const int e1 = min(e0 + PART_CHUNK, E);
    for (int e = e0 + t; e < e1; e += 256)
        atomicAdd(&hist[dst[e] >> NB_SHIFT], 1);
    __syncthreads();
    for (int i = t; i < nbuck; i += 256) {
        int c = hist[i];
        hist[i] = (c > 0) ? atomicAdd(&bcount[i], c) : 0;  // run base within bucket
    }
    __syncthreads();
    for (int e = e0 + t; e < e1; e += 256) {
        int s = src[e], d = dst[e];
        int b = d >> NB_SHIFT;
        int pos = atomicAdd(&hist[b], 1);
        pairs[(size_t)b * BCAP + pos] = make_uint2((unsigned)s, (unsigned)d);
    }
}

// Exclusive scan of bcount[nbuck] -> bbase; also rowstart[N] = E sentinel.
__global__ __launch_bounds__(1024) void scan_bcount(
    const int* __restrict__ bcount, int* __restrict__ bbase,
    int* __restrict__ rowstart, int N, int E, int nbuck) {
    __shared__ int tmp[1024];
    const int t = threadIdx.x;
    int v = (t < nbuck) ? bcount[t] : 0;
    tmp[t] = v;
    __syncthreads();
    for (int off = 1; off < 1024; off <<= 1) {
        int u = (t >= off) ? tmp[t - off] : 0;
        __syncthreads();
        tmp[t] += u;
        __syncthreads();
    }
    if (t < nbuck) bbase[t] = tmp[t] - v;  // exclusive
    if (t == 0) rowstart[N] = E;
}

// One block per bucket: LDS degree histogram -> LDS scan -> rowstart/dinv,
// then cursor fill of col (contiguous ~8KB window per bucket).
__global__ __launch_bounds__(256) void fill_csr_bucket(
    const uint2* __restrict__ pairs, const int* __restrict__ bcount,
    const int* __restrict__ bbase, int* __restrict__ rowstart,
    float* __restrict__ dinv, int* __restrict__ col, int N) {
    __shared__ int hist[128], pfx[128];
    const int b = blockIdx.x, t = threadIdx.x;
    if (t < 128) hist[t] = 0;
    __syncthreads();
    const int cnt = bcount[b];
    const uint2* pp = pairs + (size_t)b * BCAP;
    for (int e = t; e < cnt; e += 256)
        atomicAdd(&hist[pp[e].y & 127u], 1);
    __syncthreads();
    if (t < 128) pfx[t] = hist[t];
    __syncthreads();
    for (int off = 1; off < 128; off <<= 1) {
        int v = 0;
        if (t < 128 && t >= off) v = pfx[t - off];
        __syncthreads();
        if (t < 128) pfx[t] += v;
        __syncthreads();
    }
    const int base = bbase[b];
    if (t < 128) {
        int deg = hist[t];
        int start = base + pfx[t] - deg;  // exclusive within bucket
        int n = (b << NB_SHIFT) + t;
        if (n < N) {
            rowstart[n] = start;
            dinv[n] = rsqrtf((float)deg + 1.0f);  // +1 self-loop
        }
        hist[t] = start;  // becomes cursor
    }
    __syncthreads();
    for (int e = t; e < cnt; e += 256) {
        uint2 pr = pp[e];
        int pos = atomicAdd(&hist[pr.y & 127u], 1);
        col[pos] = (int)pr.x;
    }
}

// hs[row][c] = (X'[row][:] @ W[:][c]) * dinv[row], stored bf16.
// FUSE: X' = prelu(X*scale + shift, a) applied per-column during staging.
template <int K, bool FUSE>
__global__ __launch_bounds__(256) void gemm_scale(
    const float* __restrict__ X, const float* __restrict__ W,
    const float* __restrict__ dinv, const float* __restrict__ stats_prev,
    const float* __restrict__ a_prev, ushort4* __restrict__ hsb4, int N) {
    static_assert(K % 64 == 0, "K must be multiple of 64");
    __shared__ float Ws[K * 64];
    __shared__ float Xs[64 * 65];

    const int t = threadIdx.x;
    const int rowBase = blockIdx.x * 64;

    for (int q = t; q < K * 16; q += 256)
        ((float4*)Ws)[q] = ((const float4*)W)[q];

    const int tx = t & 15;
    const int ty = t >> 4;

    float acc[4][4];
#pragma unroll
    for (int i = 0; i < 4; ++i)
#pragma unroll
        for (int j = 0; j < 4; ++j) acc[i][j] = 0.f;

#pragma unroll
    for (int kh = 0; kh < K / 64; ++kh) {
        __syncthreads();
#pragma unroll
        for (int j = 0; j < 4; ++j) {
            int q = t + j * 256;
            int r = q >> 4, kk = q & 15;
            int row = rowBase + r;
            float4 v = make_float4(0.f, 0.f, 0.f, 0.f);
            if (row < N) {
                v = *(const float4*)(X + (size_t)row * K + kh * 64 + kk * 4);
                if (FUSE) {
                    int cg = kh * 16 + kk;
                    float4 sc = ((const float4*)(stats_prev + 128))[cg];
                    float4 sh = ((const float4*)(stats_prev + 192))[cg];
                    float4 av = ((const float4*)a_prev)[cg];
                    v.x = fmaf(v.x, sc.x, sh.x); v.x = v.x >= 0.f ? v.x : av.x * v.x;
                    v.y = fmaf(v.y, sc.y, sh.y); v.y = v.y >= 0.f ? v.y : av.y * v.y;
                    v.z = fmaf(v.z, sc.z, sh.z); v.z = v.z >= 0.f ? v.z : av.z * v.z;
                    v.w = fmaf(v.w, sc.w, sh.w); v.w = v.w >= 0.f ? v.w : av.w * v.w;
                }
            }
            float* p = &Xs[r * 65 + kk * 4];
            p[0] = v.x; p[1] = v.y; p[2] = v.z; p[3] = v.w;
        }
        __syncthreads();
#pragma unroll 8
        for (int k = 0; k < 64; ++k) {
            float4 w4 = *(const float4*)&Ws[(kh * 64 + k) * 64 + tx * 4];
#pragma unroll
            for (int i = 0; i < 4; ++i) {
                float xv = Xs[(ty * 4 + i) * 65 + k];
                acc[i][0] = fmaf(xv, w4.x, acc[i][0]);
                acc[i][1] = fmaf(xv, w4.y, acc[i][1]);
                acc[i][2] = fmaf(xv, w4.z, acc[i][2]);
                acc[i][3] = fmaf(xv, w4.w, acc[i][3]);
            }
        }
    }

#pragma unroll
    for (int i = 0; i < 4; ++i) {
        int row = rowBase + ty * 4 + i;
        if (row < N) {
            float dv = dinv[row];
            ushort4 o;
            o.x = f2bf(acc[i][0] * dv);
            o.y = f2bf(acc[i][1] * dv);
            o.z = f2bf(acc[i][2] * dv);
            o.w = f2bf(acc[i][3] * dv);
            hsb4[(size_t)row * 16 + tx] = o;
        }
    }
}

// One wave per node: y[n] = dinv[n]*(hs[n] + sum_{src->n} hs[src]) + b
// Register accumulation, 4-deep gather MLP; fused per-feature BN stats.
__global__ __launch_bounds__(256) void aggregate_bn(
    const ushort4* __restrict__ hsb4, const int* __restrict__ col,
    const int* __restrict__ rowstart, const float* __restrict__ dinv,
    const float* __restrict__ bias, float* __restrict__ stats,
    float4* __restrict__ y4, int N) {
    const int t = threadIdx.x;
    const int lane = t & 63;
    const int wid = t >> 6;      // wave in block (0..3)
    const int fl = lane & 15;    // float4 feature index
    const int eg = lane >> 4;    // edge subgroup (0..3)

    __shared__ float lsum[64], lsq[64];
    if (t < 64) { lsum[t] = 0.f; lsq[t] = 0.f; }
    __syncthreads();

    float4 ssum = make_float4(0.f, 0.f, 0.f, 0.f);
    float4 ssq  = make_float4(0.f, 0.f, 0.f, 0.f);
    const float4 b4 = ((const float4*)bias)[fl];
    const int waveStride = gridDim.x * 4;

    for (int n = blockIdx.x * 4 + wid; n < N; n += waveStride) {
        int start = rowstart[n];
        int deg = rowstart[n + 1] - start;
        float4 acc = make_float4(0.f, 0.f, 0.f, 0.f);
        int i = eg;
        // 4-deep MLP: 4 independent gathers in flight per lane-group
        for (; i + 12 < deg; i += 16) {
            int s0 = col[start + i];
            int s1 = col[start + i + 4];
            int s2 = col[start + i + 8];
            int s3 = col[start + i + 12];
            ushort4 r0 = hsb4[(size_t)s0 * 16 + fl];
            ushort4 r1 = hsb4[(size_t)s1 * 16 + fl];
            ushort4 r2 = hsb4[(size_t)s2 * 16 + fl];
            ushort4 r3 = hsb4[(size_t)s3 * 16 + fl];
            acc.x += (bf2f(r0.x) + bf2f(r1.x)) + (bf2f(r2.x) + bf2f(r3.x));
            acc.y += (bf2f(r0.y) + bf2f(r1.y)) + (bf2f(r2.y) + bf2f(r3.y));
            acc.z += (bf2f(r0.z) + bf2f(r1.z)) + (bf2f(r2.z) + bf2f(r3.z));
            acc.w += (bf2f(r0.w) + bf2f(r1.w)) + (bf2f(r2.w) + bf2f(r3.w));
        }
        for (; i < deg; i += 4) {
            int s = col[start + i];
            ushort4 rv = hsb4[(size_t)s * 16 + fl];
            acc.x += bf2f(rv.x); acc.y += bf2f(rv.y);
            acc.z += bf2f(rv.z); acc.w += bf2f(rv.w);
        }
        acc.x += __shfl_xor(acc.x, 16); acc.y += __shfl_xor(acc.y, 16);
        acc.z += __shfl_xor(acc.z, 16); acc.w += __shfl_xor(acc.w, 16);
        acc.x += __shfl_xor(acc.x, 32); acc.y += __shfl_xor(acc.y, 32);
        acc.z += __shfl_xor(acc.z, 32); acc.w += __shfl_xor(acc.w, 32);
        if (eg == 0) {
            ushort4 sv = hsb4[(size_t)n * 16 + fl];
            float dv = dinv[n];
            float4 yv;
            yv.x = fmaf(dv, acc.x + bf2f(sv.x), b4.x);
            yv.y = fmaf(dv, acc.y + bf2f(sv.y), b4.y);
            yv.z = fmaf(dv, acc.z + bf2f(sv.z), b4.z);
            yv.w = fmaf(dv, acc.w + bf2f(sv.w), b4.w);
            y4[(size_t)n * 16 + fl] = yv;
            ssum.x += yv.x; ssum.y += yv.y; ssum.z += yv.z; ssum.w += yv.w;
            ssq.x = fmaf(yv.x, yv.x, ssq.x); ssq.y = fmaf(yv.y, yv.y, ssq.y);
            ssq.z = fmaf(yv.z, yv.z, ssq.z); ssq.w = fmaf(yv.w, yv.w, ssq.w);
        }
    }
    if (eg == 0) {
        atomicAdd(&lsum[fl * 4 + 0], ssum.x); atomicAdd(&lsum[fl * 4 + 1], ssum.y);
        atomicAdd(&lsum[fl * 4 + 2], ssum.z); atomicAdd(&lsum[fl * 4 + 3], ssum.w);
        atomicAdd(&lsq[fl * 4 + 0], ssq.x);  atomicAdd(&lsq[fl * 4 + 1], ssq.y);
        atomicAdd(&lsq[fl * 4 + 2], ssq.z);  atomicAdd(&lsq[fl * 4 + 3], ssq.w);
    }
    __syncthreads();
    if (t < 64) atomicAdd(&stats[t], lsum[t]);
    else if (t < 128) atomicAdd(&stats[64 + (t - 64)], lsq[t - 64]);
}

__global__ void bn_final(float* __restrict__ stats, const float* __restrict__ g,
                         const float* __restrict__ be, float invN) {
    int c = threadIdx.x;  // 64 threads
    float mu = stats[c] * invN;
    float var = stats[64 + c] * invN - mu * mu;
    float sc = g[c] * rsqrtf(var + BN_EPS);
    stats[128 + c] = sc;
    stats[192 + c] = be[c] - mu * sc;
}

// final layer only: out = prelu(y*scale + shift, a)
__global__ __launch_bounds__(256) void bn_apply(
    const float4* __restrict__ y4, const float* __restrict__ stats,
    const float* __restrict__ a, float4* __restrict__ out4, int total4) {
    int i = blockIdx.x * blockDim.x + threadIdx.x;
    if (i >= total4) return;
    int cg = (i & 15) * 4;
    float4 v = y4[i];
    float4 o;
    { float z = fmaf(v.x, stats[128 + cg + 0], stats[192 + cg + 0]); o.x = z >= 0.f ? z : a[cg + 0] * z; }
    { float z = fmaf(v.y, stats[128 + cg + 1], stats[192 + cg + 1]); o.y = z >= 0.f ? z : a[cg + 1] * z; }
    { float z = fmaf(v.z, stats[128 + cg + 2], stats[192 + cg + 2]); o.z = z >= 0.f ? z : a[cg + 2] * z; }
    { float z = fmaf(v.w, stats[128 + cg + 3], stats[192 + cg + 3]); o.w = z >= 0.f ? z : a[cg + 3] * z; }
    out4[i] = o;
}

extern "C" void kernel_launch(void* const* d_in, const int* in_sizes, int n_in,
                              void* d_out, int out_size, void* d_ws, size_t ws_size,
                              hipStream_t stream) {
    const float* x  = (const float*)d_in[0];
    const int*   ei = (const int*)d_in[1];
    const int N = in_sizes[0] / 128;
    const int E = in_sizes[1] / 2;
    const int* srcp = ei;
    const int* dstp = ei + E;

    const float* W1 = (const float*)d_in[2];
    const float* b1 = (const float*)d_in[3];
    const float* g1 = (const float*)d_in[4];
    const float* be1 = (const float*)d_in[5];
    const float* a1 = (const float*)d_in[6];
    const float* W2 = (const float*)d_in[7];
    const float* b2 = (const float*)d_in[8];
    const float* g2 = (const float*)d_in[9];
    const float* be2 = (const float*)d_in[10];
    const float* a2 = (const float*)d_in[11];
    const float* W3 = (const float*)d_in[12];
    const float* b3 = (const float*)d_in[13];
    const float* g3 = (const float*)d_in[14];
    const float* be3 = (const float*)d_in[15];
    const float* a3 = (const float*)d_in[16];

    const int nbuck = (N + 127) >> NB_SHIFT;  // 782

    // ws layout (4B units):
    // dinv[N] | rowstart[N+4] | bcount[1024] | bbase[1024] | stats[768] |
    // col[E] | pairs[nbuck*BCAP*2] | hsb[N*32] | ybuf[N*64]
    float* ws = (float*)d_ws;
    float* dinv     = ws;
    int*   rowstart = (int*)(ws + N);
    int*   bcount   = (int*)(ws + 2 * (size_t)N + 4);
    int*   bbase    = bcount + 1024;
    float* stats    = (float*)(bbase + 1024);
    int*   col      = (int*)(stats + 768);
    uint2* pairs    = (uint2*)(col + E);
    float* hsbf     = (float*)(pairs + (size_t)nbuck * BCAP);
    ushort4* hsb4   = (ushort4*)hsbf;
    float* ybuf     = hsbf + (size_t)N * 32;

    float* stats1 = stats, *stats2 = stats + 256, *stats3 = stats + 512;

    // one memset covers bcount + bbase + stats (contiguous)
    hipMemsetAsync(bcount, 0, (1024 + 1024 + 768) * sizeof(int), stream);
    partition_edges<<<(E + PART_CHUNK - 1) / PART_CHUNK, 256, 0, stream>>>(
        srcp, dstp, bcount, pairs, E, nbuck);
    scan_bcount<<<1, 1024, 0, stream>>>(bcount, bbase, rowstart, N, E, nbuck);
    fill_csr_bucket<<<nbuck, 256, 0, stream>>>(pairs, bcount, bbase, rowstart,
                                               dinv, col, N);

    const int gemmGrid = (N + 63) / 64;
    const int aggGrid = 2048;
    const int applyGrid = (N * 16 + 255) / 256;
    const float invN = 1.0f / (float)N;

    // ---- layer 1 ----
    gemm_scale<128, false><<<gemmGrid, 256, 0, stream>>>(x, W1, dinv, nullptr, nullptr, hsb4, N);
    aggregate_bn<<<aggGrid, 256, 0, stream>>>(hsb4, col, rowstart, dinv, b1,
                                              stats1, (float4*)ybuf, N);
    bn_final<<<1, 64, 0, stream>>>(stats1, g1, be1, invN);

    // ---- layer 2 (BN1+PReLU1 fused into X staging) ----
    gemm_scale<64, true><<<gemmGrid, 256, 0, stream>>>(ybuf, W2, dinv, stats1, a1, hsb4, N);
    aggregate_bn<<<aggGrid, 256, 0, stream>>>(hsb4, col, rowstart, dinv, b2,
                                              stats2, (float4*)ybuf, N);
    bn_final<<<1, 64, 0, stream>>>(stats2, g2, be2, invN);

    // ---- layer 3 ----
    gemm_scale<64, true><<<gemmGrid, 256, 0, stream>>>(ybuf, W3, dinv, stats2, a2, hsb4, N);
    aggregate_bn<<<aggGrid, 256, 0, stream>>>(hsb4, col, rowstart, dinv, b3,
                                              stats3, (float4*)ybuf, N);
    bn_final<<<1, 64, 0, stream>>>(stats3, g3, be3, invN);

    bn_apply<<<applyGrid, 256, 0, stream>>>((const float4*)ybuf, stats3, a3,
                                            (float4*)d_out, N * 16);
}